// Round 8
// baseline (157.802 us; speedup 1.0000x reference)
//
#include <hip/hip_runtime.h>

// FilteredNoiseGenerator: B=32, t=4000, nbands=65, framesize=80, L_fir=129, L=208
// out[b,p] = sum_{f,m} x[b,f,m]*w[b,f,tau], tau = (p+64) - 80f - m in [0,128]
// P1 (firwin) = GEMM vs fixed matrix M (MFMA f16, M in d_ws, frag-order).
// R16: MAC-pipe switch. Busy-time accounting across R8-R15 shows a constant
//     ~29 us fdot2 core (720 fdot2/thread @ ~4 cyc: v_dot2_f32_f16 is half-
//     rate) while overhead shrank 27->7 us -- the plateau IS the MAC pipe.
//     P2 rewritten on v_pk_fma_f32 (full-rate, 2 MACs/inst):
//     - acc pairs (acc[2k],acc[2k+1]) even-m bank PA, (acc[2k-1],acc[2k])
//       odd-m bank PB: for fixed m, adjacent outputs hit adjacent-ascending
//       taps -> ONLY even-phase f32 w-pairs needed; alignbit machinery dies.
//     - w window: 16-slot f32x2 ring, period-4 named rotation (no shift movs);
//       slide = 4 b32 + 8 cvt; x = 2 b64 + 8 cvt (LDS traffic unchanged).
//     - products f16*f16 exact in f32; only summation order changes (parity
//       split, merged once at writeout): error ~1e-6 << f16 quantization.

#define NT 256
#define X_STRIDE 84        // f16 x row stride; 168 B rows (8B-aligned)
#define XPAD 8             // front pad so x prefetch (down to xr[-8]) is in-bounds
#define W_STRIDE 154       // f16 w row; 77 dw/row, gcd(77,32)=1 -> conflict-free
#define W_P 24             // w[tau] at wr[W_P+tau]; tau in [0,128]; zeros outside
#define NSLOT 35           // frames f0-2 .. f0+32
#define WTOT_H 5416        // 34*154 + 178 = 5414 max pad write; 16B-aligned total
#define XTOT_H 2948        // XPAD + 35*84

typedef _Float16 f16x8 __attribute__((ext_vector_type(8)));
typedef _Float16 f16x4 __attribute__((ext_vector_type(4)));
typedef _Float16 h2 __attribute__((ext_vector_type(2)));
typedef float f32x4 __attribute__((ext_vector_type(4)));
typedef float f32x2 __attribute__((ext_vector_type(2)));

static __device__ __forceinline__ f32x2 cv2(h2 h) {   // f16 pair -> f32 pair
  f32x2 r; r.x = (float)h.x; r.y = (float)h.y; return r;
}

// ---- init: M in MFMA B-operand frag order (R6-proven). frag (nt,ks) of 27;
// lane holds B[k = ks*32 + (lane>>4)*8 + j][n = nt*16 + (lane&15)], j=0..7.
__global__ void __launch_bounds__(256)
minit_kernel(_Float16* __restrict__ M) {
  const float TP = 6.28318530717958647692f / 129.f;
  int i = blockIdx.x * 256 + threadIdx.x;      // 54*256 = 13824 = 27*512 exactly
  int frag = i >> 9;
  int off  = i & 511;
  int lane = off >> 3, j = off & 7;
  int nt = frag / 3, ks = frag - 3 * (frag / 3);
  int n = nt * 16 + (lane & 15);
  int k = ks * 32 + (lane >> 4) * 8 + j;
  float v = 0.f;
  if (n <= 128 && k <= 64) {
    float hann = 0.5f - 0.5f * __cosf((float)n * TP);
    float sc = (k == 0 ? 1.f : 2.f) * (1.f / 129.f);
    int e = (k * (n - 64)) % 129; if (e < 0) e += 129;   // exact arg reduction
    v = hann * sc * __cosf((float)e * TP);
  }
  M[i] = (_Float16)v;
}

__global__ void __launch_bounds__(NT, 7)
fng_kernel(const float* __restrict__ Hg_, const float* __restrict__ Ng_,
           float* __restrict__ Og_, const _Float16* __restrict__ Mg) {
  __shared__ __align__(16) _Float16 sWh[WTOT_H];   // 10,832 B firwin f16
  __shared__ __align__(16) _Float16 sXh[XTOT_H];   //  5,896 B x f16, REVERSED rows

  const int t  = threadIdx.x;
  const int bx = blockIdx.x;     // 0..124 (32 output-frames each)
  const int b  = blockIdx.y;     // 0..31
  const int f0 = bx * 32;

  const int wv   = t >> 6;
  const int lane = t & 63;

  // ---- issue H loads FIRST (waves 0-2): raw f32 in regs; the wait lands at
  // P1's converts, after P0a/P0c have executed under the load latency.
  float c0[8], c1[8];
  float s64 = 0.f;
  bool  va  = false;
  {
    if (wv < 3) {
      const int quad = lane >> 4;
      const int l15  = lane & 15;
      const int fr   = f0 - 2 + wv * 16 + l15;
      va = (fr >= 0 && fr < 4000);
      const int frc  = va ? fr : 0;               // clamped addr, always valid
      const float* hr = Hg_ + (size_t)b * 260000 + (size_t)frc * 65;
      __builtin_memcpy(c0, &hr[quad * 8], 32);    // 4B-aligned safe
      __builtin_memcpy(c1, &hr[32 + quad * 8], 32);
      s64 = hr[64];
    }
  }

  // ---- P0a: zero ONLY the pad cells of sWh (disjoint from P1 data writes).
  // Pads: [0,24) front of row 0; for c in 0..34 the 25-cell run
  // [c*154+153, c*154+178). 24 + 35*25 = 899 cells.
  {
#pragma unroll
    for (int it = 0; it < 4; ++it) {
      int j = t + NT * it;
      if (j < 24) {
        sWh[j] = (_Float16)0.f;
      } else if (j < 899) {
        int jj = j - 24;
        int c = jj / 25, o = jj - 25 * c;
        sWh[c * W_STRIDE + 153 + o] = (_Float16)0.f;
      }
    }
  }

  // ---- P0c: noise -> sXh REVERSED f16 (xr[u] = 2*noise[79-u]-1) ----
  {
    const float* Ng = Ng_ + (size_t)b * 320000;
#pragma unroll
    for (int j = 0; j < 3; ++j) {
      int q = t + NT * j;
      if (q < NSLOT * 20) {
        int fi = q / 20, qm = q - 20 * fi;
        int fr = f0 - 2 + fi;
        f16x4 o = {(_Float16)0.f, (_Float16)0.f, (_Float16)0.f, (_Float16)0.f};
        if (fr >= 0 && fr < 4000) {
          float4 v = *(const float4*)&Ng[(size_t)fr * 80 + 4 * qm];
          o.x = (_Float16)(2.f * v.w - 1.f);   // x[4qm+3]
          o.y = (_Float16)(2.f * v.z - 1.f);   // x[4qm+2]
          o.z = (_Float16)(2.f * v.y - 1.f);   // x[4qm+1]
          o.w = (_Float16)(2.f * v.x - 1.f);   // x[4qm]
        }
        *(f16x4*)&sXh[XPAD + fi * X_STRIDE + (76 - 4 * qm)] = o;   // 8B-aligned
      }
    }
  }

  // ---- P1: firwin = H x M^T via MFMA 16x16x32 f16; A from the early loads ----
  {
    if (wv < 3) {
      const int quad = lane >> 4;
      const int l15  = lane & 15;
      const int mt   = wv;
      if (!va) {
#pragma unroll
        for (int j = 0; j < 8; ++j) { c0[j] = 0.f; c1[j] = 0.f; }
        s64 = 0.f;
      }
      f16x8 a0, a1, a2;
#pragma unroll
      for (int j = 0; j < 8; ++j) {
        a0[j] = (_Float16)c0[j];
        a1[j] = (_Float16)c1[j];
        a2[j] = (_Float16)0.f;
      }
      if (quad == 0) a2[0] = (_Float16)s64;       // col 64; cols 65..71 zero

#pragma unroll 3
      for (int nt = 0; nt < 9; ++nt) {
        f32x4 acc = {0.f, 0.f, 0.f, 0.f};
        f16x8 b0 = ((const f16x8*)Mg)[(nt * 3 + 0) * 64 + lane];
        f16x8 b1 = ((const f16x8*)Mg)[(nt * 3 + 1) * 64 + lane];
        f16x8 b2 = ((const f16x8*)Mg)[(nt * 3 + 2) * 64 + lane];
        acc = __builtin_amdgcn_mfma_f32_16x16x32_f16(a0, b0, acc, 0, 0, 0);
        acc = __builtin_amdgcn_mfma_f32_16x16x32_f16(a1, b1, acc, 0, 0, 0);
        acc = __builtin_amdgcn_mfma_f32_16x16x32_f16(a2, b2, acc, 0, 0, 0);
        const int n = nt * 16 + l15;
        if (n <= 128) {
          const int fb = mt * 16 + quad * 4;
#pragma unroll
          for (int r = 0; r < 4; ++r) {
            int frame = fb + r;
            if (frame < NSLOT) sWh[frame * W_STRIDE + W_P + n] = (_Float16)acc[r];
          }
        }
      }
    }
  }
  __syncthreads();   // single barrier: pads + x + w all visible

  // ------- P2: gather convolution on v_pk_fma_f32 (full-rate packed f32) -----
  // For output pair (i, i+1) and fixed m: taps (tau, tau+1) ascending-adjacent
  // -> one even-phase f32 w-pair. even m -> bank PA (acc[2k],acc[2k+1]);
  // odd m -> bank PB (acc[2k-1],acc[2k]) (PB0.x / PB5.y are dummies).
  // Window: f32x2 pairs W[j'], j'=0..8, pair j' covers taps
  // tau = dlt-8U-8+2j' + {0,1}; slide 4 pairs/trip on a 16-name ring
  // (period 4, zero shift movs). Trip: 4 b32 w + 2 b64 x + 16 cvt + 44 pk_fma.
  {
    const int col = t & 31;
    const int pb  = t >> 5;
    const int e   = 64 + 10 * pb;
    const int qq  = (e >= 80) ? 1 : 0;
    const int D   = e - 80 * qq;                    // per half-wave uniform, even
    f32x2 PA0 = {0.f, 0.f}, PA1 = {0.f, 0.f}, PA2 = {0.f, 0.f},
          PA3 = {0.f, 0.f}, PA4 = {0.f, 0.f};
    f32x2 PB0 = {0.f, 0.f}, PB1 = {0.f, 0.f}, PB2 = {0.f, 0.f},
          PB3 = {0.f, 0.f}, PB4 = {0.f, 0.f}, PB5 = {0.f, 0.f};

#define PK(P, X, W) P = __builtin_elementwise_fma(X, W, P)
// one trip: issue next-trip loads, cvt current x, 44 pk_fma (s=m ascending ->
// per-acc-lane order = m ascending), cvt fresh w pairs into next ring slots.
#define TRIP(W0,W1,W2,W3,W4,W5,W6,W7,W8, F0,F1,F2,F3, QC0,QC1, QN0,QN1)      \
  { h2 t0_ = *(const h2*)&wq[-8]; h2 t1_ = *(const h2*)&wq[-6];               \
    h2 t2_ = *(const h2*)&wq[-4]; h2 t3_ = *(const h2*)&wq[-2];               \
    xp -= 8;                                                                  \
    QN0 = *(const f16x4*)&xp[0];                                              \
    QN1 = *(const f16x4*)&xp[4];                                              \
    float xs0 = (float)QC1.w, xs1 = (float)QC1.z;                             \
    float xs2 = (float)QC1.y, xs3 = (float)QC1.x;                             \
    float xs4 = (float)QC0.w, xs5 = (float)QC0.z;                             \
    float xs6 = (float)QC0.y, xs7 = (float)QC0.x;                             \
    f32x2 X;                                                                  \
    X.x = xs0; X.y = xs0;                                                     \
    PK(PA0,X,W4); PK(PA1,X,W5); PK(PA2,X,W6); PK(PA3,X,W7); PK(PA4,X,W8);     \
    X.x = xs1; X.y = xs1;                                                     \
    PK(PB0,X,W3); PK(PB1,X,W4); PK(PB2,X,W5); PK(PB3,X,W6); PK(PB4,X,W7);     \
    PK(PB5,X,W8);                                                             \
    X.x = xs2; X.y = xs2;                                                     \
    PK(PA0,X,W3); PK(PA1,X,W4); PK(PA2,X,W5); PK(PA3,X,W6); PK(PA4,X,W7);     \
    X.x = xs3; X.y = xs3;                                                     \
    PK(PB0,X,W2); PK(PB1,X,W3); PK(PB2,X,W4); PK(PB3,X,W5); PK(PB4,X,W6);     \
    PK(PB5,X,W7);                                                             \
    X.x = xs4; X.y = xs4;                                                     \
    PK(PA0,X,W2); PK(PA1,X,W3); PK(PA2,X,W4); PK(PA3,X,W5); PK(PA4,X,W6);     \
    X.x = xs5; X.y = xs5;                                                     \
    PK(PB0,X,W1); PK(PB1,X,W2); PK(PB2,X,W3); PK(PB3,X,W4); PK(PB4,X,W5);     \
    PK(PB5,X,W6);                                                             \
    X.x = xs6; X.y = xs6;                                                     \
    PK(PA0,X,W1); PK(PA1,X,W2); PK(PA2,X,W3); PK(PA3,X,W4); PK(PA4,X,W5);     \
    X.x = xs7; X.y = xs7;                                                     \
    PK(PB0,X,W0); PK(PB1,X,W1); PK(PB2,X,W2); PK(PB3,X,W3); PK(PB4,X,W4);     \
    PK(PB5,X,W5);                                                             \
    F0 = cv2(t0_); F1 = cv2(t1_); F2 = cv2(t2_); F3 = cv2(t3_);               \
    wq -= 8; }

#pragma unroll 1
    for (int g = 2; g >= -1; --g) {                 // source frame F - g
      const int dlt = D + 80 * g;                   // even
      int Ulo = (dlt - 128) >> 3; if (Ulo < 0) Ulo = 0;
      int Uhi = (dlt + 9) >> 3;   if (Uhi > 9) Uhi = 9;
      if (Ulo > Uhi) continue;
      const int slot = col + qq - g + 2;            // 0..34
      const _Float16* wr = &sWh[slot * W_STRIDE];
      const _Float16* xr = &sXh[XPAD + slot * X_STRIDE];

      // head: 9 w pairs (pos = 16+dlt-8Ulo+2j', j'=0..8; min pos 10 >= 0,
      // max 164 -> all overreads land in zeroed pads) + first x quads.
      const _Float16* wq = wr + (16 + dlt - 8 * Ulo);
      f32x2 R0 = cv2(*(const h2*)&wq[0]);
      f32x2 R1 = cv2(*(const h2*)&wq[2]);
      f32x2 R2 = cv2(*(const h2*)&wq[4]);
      f32x2 R3 = cv2(*(const h2*)&wq[6]);
      f32x2 R4 = cv2(*(const h2*)&wq[8]);
      f32x2 R5 = cv2(*(const h2*)&wq[10]);
      f32x2 R6 = cv2(*(const h2*)&wq[12]);
      f32x2 R7 = cv2(*(const h2*)&wq[14]);
      f32x2 R8 = cv2(*(const h2*)&wq[16]);
      f32x2 R9, R10, R11, R12, R13, R14, R15;       // filled by ring before read
      const _Float16* xp = &xr[72 - 8 * Ulo];
      f16x4 qa0 = *(const f16x4*)&xp[0];            // (x7,x6,x5,x4) of m=8U+..
      f16x4 qa1 = *(const f16x4*)&xp[4];            // (x3,x2,x1,x0)
      f16x4 qb0, qb1;

      int U = Ulo;
      for (;;) {
        TRIP(R0,R1,R2,R3,R4,R5,R6,R7,R8,    R12,R13,R14,R15, qa0,qa1, qb0,qb1)
        if (++U > Uhi) break;
        TRIP(R12,R13,R14,R15,R0,R1,R2,R3,R4, R8,R9,R10,R11,  qb0,qb1, qa0,qa1)
        if (++U > Uhi) break;
        TRIP(R8,R9,R10,R11,R12,R13,R14,R15,R0, R4,R5,R6,R7,  qa0,qa1, qb0,qb1)
        if (++U > Uhi) break;
        TRIP(R4,R5,R6,R7,R8,R9,R10,R11,R12,  R0,R1,R2,R3,    qb0,qb1, qa0,qa1)
        if (++U > Uhi) break;
      }
    }
#undef TRIP
#undef PK

    // merge parity banks (one add per output) + exactly-once writeout:
    // u0 = 80*col + 10*pb (even -> float2 stores)
    float o0 = PA0.x + PB0.y, o1 = PA0.y + PB1.x;
    float o2 = PA1.x + PB1.y, o3 = PA1.y + PB2.x;
    float o4 = PA2.x + PB2.y, o5 = PA2.y + PB3.x;
    float o6 = PA3.x + PB3.y, o7 = PA3.y + PB4.x;
    float o8 = PA4.x + PB4.y, o9 = PA4.y + PB5.x;
    float* Ob = Og_ + (size_t)b * 320000 + 2560 * bx + 80 * col + 10 * pb;
    float2 v0; v0.x = o0; v0.y = o1; *(float2*)&Ob[0] = v0;
    float2 v1; v1.x = o2; v1.y = o3; *(float2*)&Ob[2] = v1;
    float2 v2; v2.x = o4; v2.y = o5; *(float2*)&Ob[4] = v2;
    float2 v3; v3.x = o6; v3.y = o7; *(float2*)&Ob[6] = v3;
    float2 v4; v4.x = o8; v4.y = o9; *(float2*)&Ob[8] = v4;
  }
}

extern "C" void kernel_launch(void* const* d_in, const int* in_sizes, int n_in,
                              void* d_out, int out_size, void* d_ws, size_t ws_size,
                              hipStream_t stream) {
  const float* H     = (const float*)d_in[0];   // [32,4000,65] fp32
  const float* noise = (const float*)d_in[1];   // [32,4000,80] fp32
  float* out = (float*)d_out;                   // [32,320000] fp32
  _Float16* M = (_Float16*)d_ws;                // 27,648 B of scratch
  (void)in_sizes; (void)n_in; (void)ws_size; (void)out_size;

  minit_kernel<<<54, 256, 0, stream>>>(M);      // rebuilt every call (ws re-poisoned)
  dim3 grid(125, 32, 1);
  fng_kernel<<<grid, NT, 0, stream>>>(H, noise, out, M);
}